// Round 1
// baseline (31877.197 us; speedup 1.0000x reference)
//
#include <hip/hip_runtime.h>
#include <hip/hip_bf16.h>

// LSTM decoder: B=64, E=H=1024, 4H=4096, T=1024, L=3, O=64.
// Pipelined over layers: launch s in [0,1027); layer l handles t=s-l; block 192
// projects h2[s-3] to the output. Weights/h fp16, c + accum fp32.

typedef _Float16 v8h __attribute__((ext_vector_type(8)));
typedef _Float16 v4h __attribute__((ext_vector_type(4)));
typedef float v4f __attribute__((ext_vector_type(4)));
typedef float v4fs __attribute__((ext_vector_type(4)));

#define B64 64
#define H1K 1024
#define G4K 4096
#define TSTEPS 1024

__global__ void cvt4_kernel(const float* __restrict__ s, _Float16* __restrict__ d, int n4) {
    int i = blockIdx.x * blockDim.x + threadIdx.x;
    int stride = gridDim.x * blockDim.x;
    for (; i < n4; i += stride) {
        v4fs v = ((const v4fs*)s)[i];
        v4h o;
        o[0] = (_Float16)v[0]; o[1] = (_Float16)v[1];
        o[2] = (_Float16)v[2]; o[3] = (_Float16)v[3];
        ((v4h*)d)[i] = o;
    }
}

// states: hbuf [3][2][64][1024] f16 (slot t&1), cbuf [3][64][1024] f32
__global__ void init_kernel(const float* __restrict__ h0, const float* __restrict__ c0,
                            _Float16* __restrict__ hbuf, float* __restrict__ cbuf) {
    int i = blockIdx.x * 256 + threadIdx.x;   // grid 768*256 = 196608 exact
    int l = i >> 16, rem = i & 65535;
    cbuf[i] = c0[i];
    hbuf[(l * 2 + 1) * 65536 + rem] = (_Float16)h0[i];  // slot 1 == h[-1]
}

__global__ void bias_kernel(const float* __restrict__ b_ih, const float* __restrict__ b_hh,
                            float* __restrict__ bias12) {
    int i = blockIdx.x * 256 + threadIdx.x;   // 8192
    int layer = (i >> 12) + 1, g = i & 4095;
    bias12[i] = b_ih[layer * 4096 + g] + b_hh[layer * 4096 + g];
}

// xp0[b][g] = enc16 @ Wih0^T + b_ih0 + b_hh0   (64 blocks x 64 gates)
__global__ __launch_bounds__(256) void xp0_kernel(
    const _Float16* __restrict__ enc16, const _Float16* __restrict__ Wih,
    const float* __restrict__ b_ih, const float* __restrict__ b_hh,
    float* __restrict__ xp0) {
    __shared__ float red[16384];
    const int tid = threadIdx.x, bx = blockIdx.x;
    const int ln = tid & 63, w = tid >> 6, lm = ln & 15, q = ln >> 4;
    v4f acc[4][4] = {};
    for (int kb = 0; kb < 8; ++kb) {
        int kk = (w + 4 * kb) * 32 + q * 8;
        v8h af[4], bf[4];
#pragma unroll
        for (int mt = 0; mt < 4; ++mt) af[mt] = *(const v8h*)(enc16 + (mt * 16 + lm) * 1024 + kk);
#pragma unroll
        for (int nt = 0; nt < 4; ++nt) bf[nt] = *(const v8h*)(Wih + (bx * 64 + nt * 16 + lm) * 1024 + kk);
#pragma unroll
        for (int mt = 0; mt < 4; ++mt)
#pragma unroll
            for (int nt = 0; nt < 4; ++nt)
                acc[mt][nt] = __builtin_amdgcn_mfma_f32_16x16x32_f16(af[mt], bf[nt], acc[mt][nt], 0, 0, 0);
    }
#pragma unroll
    for (int mt = 0; mt < 4; ++mt) if (mt != w)
#pragma unroll
        for (int nt = 0; nt < 4; ++nt)
            *(v4f*)&red[((w * 16 + mt * 4 + nt) * 64 + ln) * 4] = acc[mt][nt];
    __syncthreads();
#pragma unroll
    for (int ww = 0; ww < 4; ++ww) if (ww != w)
#pragma unroll
        for (int nt = 0; nt < 4; ++nt)
            acc[w][nt] += *(const v4f*)&red[((ww * 16 + w * 4 + nt) * 64 + ln) * 4];
#pragma unroll
    for (int nt = 0; nt < 4; ++nt) {
        int g = bx * 64 + nt * 16 + lm;
        float bb = b_ih[g] + b_hh[g];
#pragma unroll
        for (int r = 0; r < 4; ++r) {
            int b = w * 16 + q * 4 + r;
            xp0[b * 4096 + g] = acc[w][nt][r] + bb;
        }
    }
}

// Fused pipelined step. blocks 0..191: (l = bx>>6, 16 hidden units each).
// block 192: output projection of t = s-3.
__global__ __launch_bounds__(256) void step_kernel(
    int s,
    const _Float16* __restrict__ Wih,   // [3][4096][1024]
    const _Float16* __restrict__ Whh,   // [3][4096][1024]
    const _Float16* __restrict__ Wlin,  // [64][1024]
    const float* __restrict__ xp0,      // [64][4096]
    const float* __restrict__ bias12,   // [2][4096]
    _Float16* __restrict__ hbuf,        // [3][2][64][1024]
    float* __restrict__ cbuf,           // [3][64][1024]
    const float* __restrict__ blin,     // [64]
    float* __restrict__ out)            // [64][1024][64]
{
    __shared__ float red[16384];
    const int tid = threadIdx.x;
    const int ln = tid & 63, w = tid >> 6, lm = ln & 15, q = ln >> 4;
    v4f acc[4][4] = {};

    if (blockIdx.x == 192) {
        // ---- projection of h2[t], t = s-3 ----
        int t = s - 3;
        if (t < 0 || t >= TSTEPS) return;
        const _Float16* A = hbuf + (4 + (t & 1)) * 65536;
        for (int kb = 0; kb < 8; ++kb) {
            int kk = (w + 4 * kb) * 32 + q * 8;
            v8h af[4], bf[4];
#pragma unroll
            for (int mt = 0; mt < 4; ++mt) af[mt] = *(const v8h*)(A + (mt * 16 + lm) * 1024 + kk);
#pragma unroll
            for (int nt = 0; nt < 4; ++nt) bf[nt] = *(const v8h*)(Wlin + (nt * 16 + lm) * 1024 + kk);
#pragma unroll
            for (int mt = 0; mt < 4; ++mt)
#pragma unroll
                for (int nt = 0; nt < 4; ++nt)
                    acc[mt][nt] = __builtin_amdgcn_mfma_f32_16x16x32_f16(af[mt], bf[nt], acc[mt][nt], 0, 0, 0);
        }
#pragma unroll
        for (int mt = 0; mt < 4; ++mt) if (mt != w)
#pragma unroll
            for (int nt = 0; nt < 4; ++nt)
                *(v4f*)&red[((w * 16 + mt * 4 + nt) * 64 + ln) * 4] = acc[mt][nt];
        __syncthreads();
#pragma unroll
        for (int ww = 0; ww < 4; ++ww) if (ww != w)
#pragma unroll
            for (int nt = 0; nt < 4; ++nt)
                acc[w][nt] += *(const v4f*)&red[((ww * 16 + w * 4 + nt) * 64 + ln) * 4];
#pragma unroll
        for (int nt = 0; nt < 4; ++nt) {
            int o = nt * 16 + lm;
            float bl = blin[o];
#pragma unroll
            for (int r = 0; r < 4; ++r) {
                int b = w * 16 + q * 4 + r;
                out[b * (TSTEPS * 64) + t * 64 + o] = acc[w][nt][r] + bl;
            }
        }
        return;
    }

    // ---- LSTM layer step ----
    const int l = blockIdx.x >> 6, slice = blockIdx.x & 63;
    const int t = s - l;
    if (t < 0 || t >= TSTEPS) return;
    const int g0 = slice * 16;

    for (int ph = (l == 0 ? 1 : 0); ph < 2; ++ph) {
        const _Float16* A = (ph == 0)
            ? hbuf + ((l - 1) * 2 + (t & 1)) * 65536        // x input = h_{l-1}[t]
            : hbuf + (l * 2 + ((t - 1) & 1)) * 65536;        // recurrent h_l[t-1]
        const _Float16* W = ((ph == 0) ? Wih : Whh) + l * 4194304;
        for (int kb = 0; kb < 8; ++kb) {
            int kk = (w + 4 * kb) * 32 + q * 8;
            v8h af[4], bf[4];
#pragma unroll
            for (int mt = 0; mt < 4; ++mt) af[mt] = *(const v8h*)(A + (mt * 16 + lm) * 1024 + kk);
#pragma unroll
            for (int nt = 0; nt < 4; ++nt) bf[nt] = *(const v8h*)(W + (nt * 1024 + g0 + lm) * 1024 + kk);
#pragma unroll
            for (int mt = 0; mt < 4; ++mt)
#pragma unroll
                for (int nt = 0; nt < 4; ++nt)
                    acc[mt][nt] = __builtin_amdgcn_mfma_f32_16x16x32_f16(af[mt], bf[nt], acc[mt][nt], 0, 0, 0);
        }
    }
    // cross-wave K reduction: wave w keeps tiles mt==w
#pragma unroll
    for (int mt = 0; mt < 4; ++mt) if (mt != w)
#pragma unroll
        for (int nt = 0; nt < 4; ++nt)
            *(v4f*)&red[((w * 16 + mt * 4 + nt) * 64 + ln) * 4] = acc[mt][nt];
    __syncthreads();
#pragma unroll
    for (int ww = 0; ww < 4; ++ww) if (ww != w)
#pragma unroll
        for (int nt = 0; nt < 4; ++nt)
            acc[w][nt] += *(const v4f*)&red[((ww * 16 + w * 4 + nt) * 64 + ln) * 4];

    // activations + state update (gate order: i, f, g, o)
    const int hj = g0 + lm;
#pragma unroll
    for (int r = 0; r < 4; ++r) {
        int b = w * 16 + q * 4 + r;
        float gi = acc[w][0][r], gf = acc[w][1][r], gg = acc[w][2][r], go = acc[w][3][r];
        if (l == 0) {
            const float* xp = xp0 + b * 4096;
            gi += xp[hj]; gf += xp[1024 + hj]; gg += xp[2048 + hj]; go += xp[3072 + hj];
        } else {
            const float* bp = bias12 + (l - 1) * 4096;
            gi += bp[hj]; gf += bp[1024 + hj]; gg += bp[2048 + hj]; go += bp[3072 + hj];
        }
        gi = 1.f / (1.f + __expf(-gi));
        gf = 1.f / (1.f + __expf(-gf));
        go = 1.f / (1.f + __expf(-go));
        gg = tanhf(gg);
        float* cp = cbuf + (l * 64 + b) * 1024 + hj;
        float c = gf * (*cp) + gi * gg;
        *cp = c;
        hbuf[((l * 2 + (t & 1)) * 64 + b) * 1024 + hj] = (_Float16)(go * tanhf(c));
    }
}

extern "C" void kernel_launch(void* const* d_in, const int* in_sizes, int n_in,
                              void* d_out, int out_size, void* d_ws, size_t ws_size,
                              hipStream_t stream) {
    const float* enc   = (const float*)d_in[0];
    const float* h0    = (const float*)d_in[1];
    const float* c0    = (const float*)d_in[2];
    const float* W_ih  = (const float*)d_in[3];
    const float* W_hh  = (const float*)d_in[4];
    const float* b_ih  = (const float*)d_in[5];
    const float* b_hh  = (const float*)d_in[6];
    const float* W_lin = (const float*)d_in[7];
    const float* b_lin = (const float*)d_in[8];
    float* out = (float*)d_out;
    char* ws = (char*)d_ws;

    // ws layout (bytes) — total ~53.2 MB
    _Float16* Wih16  = (_Float16*)(ws);                 // 3*4096*1024*2 = 25165824
    _Float16* Whh16  = (_Float16*)(ws + 25165824);      // +25165824
    _Float16* Wlin16 = (_Float16*)(ws + 50331648);      // +131072
    _Float16* enc16  = (_Float16*)(ws + 50462720);      // +131072
    float*    xp0    = (float*)   (ws + 50593792);      // +1048576
    float*    bias12 = (float*)   (ws + 51642368);      // +32768
    _Float16* hbuf   = (_Float16*)(ws + 51675136);      // +786432
    float*    cbuf   = (float*)   (ws + 52461568);      // +786432

    cvt4_kernel<<<2048, 256, 0, stream>>>(W_ih, Wih16, 3145728);
    cvt4_kernel<<<2048, 256, 0, stream>>>(W_hh, Whh16, 3145728);
    cvt4_kernel<<<64, 256, 0, stream>>>(W_lin, Wlin16, 16384);
    cvt4_kernel<<<64, 256, 0, stream>>>(enc, enc16, 16384);
    init_kernel<<<768, 256, 0, stream>>>(h0, c0, hbuf, cbuf);
    bias_kernel<<<32, 256, 0, stream>>>(b_ih, b_hh, bias12);
    xp0_kernel<<<64, 256, 0, stream>>>(enc16, Wih16, b_ih, b_hh, xp0);

    for (int s = 0; s < TSTEPS + 3; ++s)
        step_kernel<<<193, 256, 0, stream>>>(s, Wih16, Whh16, Wlin16, xp0, bias12,
                                             hbuf, cbuf, b_lin, out);
}